// Round 2
// baseline (677.147 us; speedup 1.0000x reference)
//
#include <hip/hip_runtime.h>
#include <hip/hip_bf16.h>
#include <math.h>

// Problem constants
#define B 4
#define N 1024
#define C 768
#define H 8
#define D 96           // C/H
#define SIMG 16        // image side, 3*16*16 = 768

// ---------------------------------------------------------------------------
// Kernel 1: per-token 3x3 conv, SAME padding, on (3,16,16) images.
// grid.x = B*N tokens, block = 256 (one thread per pixel, 3 output channels).
// ---------------------------------------------------------------------------
__global__ __launch_bounds__(256) void conv_tok(const float* __restrict__ x,
                                                const float* __restrict__ w,
                                                float* __restrict__ out) {
    __shared__ float sx[768];
    __shared__ float sw[81];
    int t = blockIdx.x;
    const float* xt = x + (size_t)t * 768;
    int tid = threadIdx.x;
    sx[tid]       = xt[tid];
    sx[tid + 256] = xt[tid + 256];
    sx[tid + 512] = xt[tid + 512];
    if (tid < 81) sw[tid] = w[tid];
    __syncthreads();
    int p = tid;
    int i = p >> 4;
    int j = p & 15;
    float acc0 = 0.f, acc1 = 0.f, acc2 = 0.f;
    #pragma unroll
    for (int c = 0; c < 3; ++c) {
        #pragma unroll
        for (int di = 0; di < 3; ++di) {
            int ii = i + di - 1;
            if (ii < 0 || ii > 15) continue;
            #pragma unroll
            for (int dj = 0; dj < 3; ++dj) {
                int jj = j + dj - 1;
                if (jj < 0 || jj > 15) continue;
                float xv = sx[c * 256 + ii * 16 + jj];
                acc0 += xv * sw[(0 * 3 + c) * 9 + di * 3 + dj];
                acc1 += xv * sw[(1 * 3 + c) * 9 + di * 3 + dj];
                acc2 += xv * sw[(2 * 3 + c) * 9 + di * 3 + dj];
            }
        }
    }
    float* ot = out + (size_t)t * 768;
    ot[0 * 256 + p] = acc0;
    ot[1 * 256 + p] = acc1;
    ot[2 * 256 + p] = acc2;
}

// ---------------------------------------------------------------------------
// Kernel 2: S[z][n][m] = scale * dot(qc[b,n,h*96:..], kc[b,m,h*96:..])
// z = blockIdx.z; b = b0 + (z>>3); h = z&7. Batched mode: grid.z = 8*B, b0=0.
// Serial mode: grid.z = 8, b0 = b. 64x64 tile, 4x4 micro, block 256.
// ---------------------------------------------------------------------------
__global__ __launch_bounds__(256) void qk_kernel(const float* __restrict__ qc,
                                                 const float* __restrict__ kc,
                                                 float* __restrict__ S, int b0) {
    __shared__ float sQ[64][97];
    __shared__ float sK[64][97];
    int n0 = blockIdx.x * 64, m0 = blockIdx.y * 64;
    int z = blockIdx.z;
    int b = b0 + (z >> 3), h = z & 7;
    int tid = threadIdx.x, tx = tid & 15, ty = tid >> 4;
    const float* qb = qc + ((size_t)b * N + n0) * C + h * D;
    const float* kb = kc + ((size_t)b * N + m0) * C + h * D;
    for (int idx = tid; idx < 64 * 96; idx += 256) {
        int r = idx / 96, dd = idx - r * 96;
        sQ[r][dd] = qb[(size_t)r * C + dd];
        sK[r][dd] = kb[(size_t)r * C + dd];
    }
    __syncthreads();
    float acc[4][4] = {};
    for (int kk = 0; kk < 96; ++kk) {
        float a[4], c[4];
        #pragma unroll
        for (int r = 0; r < 4; ++r) a[r] = sQ[ty * 4 + r][kk];
        #pragma unroll
        for (int q2 = 0; q2 < 4; ++q2) c[q2] = sK[tx * 4 + q2][kk];
        #pragma unroll
        for (int r = 0; r < 4; ++r)
            #pragma unroll
            for (int q2 = 0; q2 < 4; ++q2)
                acc[r][q2] += a[r] * c[q2];
    }
    const float scale = 0.10206207261596577f;  // 96^-0.5
    float* Sp = S + (size_t)z * N * N;
    #pragma unroll
    for (int r = 0; r < 4; ++r) {
        float4 o = make_float4(acc[r][0] * scale, acc[r][1] * scale,
                               acc[r][2] * scale, acc[r][3] * scale);
        *reinterpret_cast<float4*>(&Sp[(size_t)(n0 + ty * 4 + r) * N + m0 + tx * 4]) = o;
    }
}

// ---------------------------------------------------------------------------
// Kernel 3: in-place softmax over m per (h,n), then re-attention head mix:
//   A'[g][n][m] = sum_h w2[g][h]*softmax(S)[h][n][m] + c_g
// grid (N, nb); blockIdx.y selects the batch slab of S. 256 threads.
// ---------------------------------------------------------------------------
__global__ __launch_bounds__(256) void softmax_reattn(float* __restrict__ S,
                                                      const float* __restrict__ rw,
                                                      const float* __restrict__ rb,
                                                      const float* __restrict__ gamma,
                                                      const float* __restrict__ beta) {
    __shared__ float rows[8][1024];
    __shared__ float red[256];
    __shared__ float Lsh[8];
    __shared__ float w2[64], cg[8];
    float* Sb = S + (size_t)blockIdx.y * H * N * N;
    int n = blockIdx.x;
    int tid = threadIdx.x;
    for (int h = 0; h < 8; ++h) {
        const float* src = Sb + (size_t)h * N * N + (size_t)n * N;
        for (int m = tid; m < 1024; m += 256) rows[h][m] = src[m];
    }
    if (tid < 64) {
        int g = tid >> 3, h = tid & 7;
        float gp = gamma[g] * rsqrtf(1.0f + 1e-5f);
        w2[tid] = gp * rw[g * 8 + h];
        if (h == 0) cg[g] = gp * rb[g] + beta[g];
    }
    __syncthreads();
    for (int h = 0; h < 8; ++h) {
        float lm = -INFINITY;
        for (int m = tid; m < 1024; m += 256) lm = fmaxf(lm, rows[h][m]);
        red[tid] = lm;
        __syncthreads();
        for (int s = 128; s > 0; s >>= 1) {
            if (tid < s) red[tid] = fmaxf(red[tid], red[tid + s]);
            __syncthreads();
        }
        float mh = red[0];
        __syncthreads();
        float ls = 0.f;
        for (int m = tid; m < 1024; m += 256) {
            float e = expf(rows[h][m] - mh);
            rows[h][m] = e;          // store exp once; reused in mix pass
            ls += e;
        }
        red[tid] = ls;
        __syncthreads();
        for (int s = 128; s > 0; s >>= 1) {
            if (tid < s) red[tid] += red[tid + s];
            __syncthreads();
        }
        if (tid == 0) Lsh[h] = 1.0f / red[0];
        __syncthreads();
    }
    for (int m = tid; m < 1024; m += 256) {
        float a[8];
        #pragma unroll
        for (int h = 0; h < 8; ++h) a[h] = rows[h][m] * Lsh[h];
        #pragma unroll
        for (int g = 0; g < 8; ++g) {
            float acc = cg[g];
            #pragma unroll
            for (int h = 0; h < 8; ++h) acc += w2[g * 8 + h] * a[h];
            Sb[(size_t)g * N * N + (size_t)n * N + m] = acc;
        }
    }
}

// ---------------------------------------------------------------------------
// Kernel 4: x[b,n, g*96+dd] = sum_m A'[g][n][m] * vc[b,m,g*96+dd]
// grid (16 ntiles, 8 heads, nb); b = b0 + blockIdx.z. tile n=64 x d=96.
// ---------------------------------------------------------------------------
__global__ __launch_bounds__(256) void pv_kernel(const float* __restrict__ S,
                                                 const float* __restrict__ vc,
                                                 float* __restrict__ xout, int b0) {
    __shared__ float sA[64][65];
    __shared__ float sV[64][96];
    int n0 = blockIdx.x * 64, g = blockIdx.y;
    int z = blockIdx.z;
    int b = b0 + z;
    int tid = threadIdx.x, tx = tid & 15, ty = tid >> 4;
    float acc[4][6] = {};
    const float* Sg = S + ((size_t)z * H + g) * N * N;
    for (int m0 = 0; m0 < 1024; m0 += 64) {
        for (int idx = tid; idx < 64 * 64; idx += 256) {
            int r = idx >> 6, mm = idx & 63;
            sA[r][mm] = Sg[(size_t)(n0 + r) * N + m0 + mm];
        }
        for (int idx = tid; idx < 64 * 96; idx += 256) {
            int r = idx / 96, dd = idx - r * 96;
            sV[r][dd] = vc[((size_t)b * N + m0 + r) * C + g * D + dd];
        }
        __syncthreads();
        for (int mm = 0; mm < 64; ++mm) {
            float a[4], vv[6];
            #pragma unroll
            for (int r = 0; r < 4; ++r) a[r] = sA[ty * 4 + r][mm];
            #pragma unroll
            for (int c = 0; c < 6; ++c) vv[c] = sV[mm][tx * 6 + c];
            #pragma unroll
            for (int r = 0; r < 4; ++r)
                #pragma unroll
                for (int c = 0; c < 6; ++c)
                    acc[r][c] += a[r] * vv[c];
        }
        __syncthreads();
    }
    #pragma unroll
    for (int r = 0; r < 4; ++r)
        #pragma unroll
        for (int c = 0; c < 6; ++c)
            xout[((size_t)b * N + n0 + ty * 4 + r) * C + g * D + tx * 6 + c] = acc[r][c];
}

// ---------------------------------------------------------------------------
// Kernel 5: out[t, c'] = pb[c'] + sum_c x[t,c] * pw[c',c]
// grid (64 t-tiles, 12 c'-tiles); 64x64 tile, k-chunks of 32, micro 4x4.
// ---------------------------------------------------------------------------
__global__ __launch_bounds__(256) void proj_kernel(const float* __restrict__ x,
                                                   const float* __restrict__ pw,
                                                   const float* __restrict__ pb,
                                                   float* __restrict__ out) {
    __shared__ float sX[64][33];
    __shared__ float sW[64][33];
    int t0 = blockIdx.x * 64, c0 = blockIdx.y * 64;
    int tid = threadIdx.x, tx = tid & 15, ty = tid >> 4;
    float acc[4][4] = {};
    for (int k0 = 0; k0 < 768; k0 += 32) {
        for (int idx = tid; idx < 64 * 32; idx += 256) {
            int r = idx >> 5, kk = idx & 31;
            sX[r][kk] = x[(size_t)(t0 + r) * C + k0 + kk];
            sW[r][kk] = pw[(size_t)(c0 + r) * C + k0 + kk];
        }
        __syncthreads();
        for (int kk = 0; kk < 32; ++kk) {
            float a[4], wv[4];
            #pragma unroll
            for (int r = 0; r < 4; ++r) a[r] = sX[ty * 4 + r][kk];
            #pragma unroll
            for (int c = 0; c < 4; ++c) wv[c] = sW[tx * 4 + c][kk];
            #pragma unroll
            for (int r = 0; r < 4; ++r)
                #pragma unroll
                for (int c = 0; c < 4; ++c)
                    acc[r][c] += a[r] * wv[c];
        }
        __syncthreads();
    }
    #pragma unroll
    for (int r = 0; r < 4; ++r) {
        int t = t0 + ty * 4 + r;
        #pragma unroll
        for (int c = 0; c < 4; ++c) {
            int cc = c0 + tx * 4 + c;
            out[(size_t)t * C + cc] = acc[r][c] + pb[cc];
        }
    }
}

// ---------------------------------------------------------------------------
extern "C" void kernel_launch(void* const* d_in, const int* in_sizes, int n_in,
                              void* d_out, int out_size, void* d_ws, size_t ws_size,
                              hipStream_t stream) {
    const float* q     = (const float*)d_in[0];
    const float* k     = (const float*)d_in[1];
    const float* v     = (const float*)d_in[2];
    const float* qw    = (const float*)d_in[3];
    const float* kw    = (const float*)d_in[4];
    const float* vw    = (const float*)d_in[5];
    const float* rw    = (const float*)d_in[6];
    const float* rb    = (const float*)d_in[7];
    const float* gamma = (const float*)d_in[8];
    const float* beta  = (const float*)d_in[9];
    const float* pw    = (const float*)d_in[10];
    const float* pb    = (const float*)d_in[11];
    float* out = (float*)d_out;

    const size_t NT = (size_t)B * N;                    // 4096 tokens
    const size_t qkv_f = 3 * NT * C;                    // 9,437,184
    const size_t S1 = (size_t)H * N * N;                // 8,388,608 (one batch)
    const size_t SB = (size_t)B * H * N * N;            // 33,554,432 (all batches)
    const size_t batched_bytes = (qkv_f + SB + NT * C) * 4;   // ~185 MB
    const bool batched = ws_size >= batched_bytes;

    float* ws = (float*)d_ws;
    float* qc = ws;
    float* kc = qc + NT * C;
    float* vc = kc + NT * C;
    float* S  = vc + NT * C;
    float* xb = S + (batched ? SB : S1);

    conv_tok<<<dim3(B * N), dim3(256), 0, stream>>>(q, qw, qc);
    conv_tok<<<dim3(B * N), dim3(256), 0, stream>>>(k, kw, kc);
    conv_tok<<<dim3(B * N), dim3(256), 0, stream>>>(v, vw, vc);

    if (batched) {
        // One dispatch per stage covering all 4 batches — maximizes occupancy
        // (same-stream kernels serialize, so cross-batch overlap must be in-grid).
        qk_kernel<<<dim3(16, 16, 8 * B), dim3(256), 0, stream>>>(qc, kc, S, 0);
        softmax_reattn<<<dim3(N, B), dim3(256), 0, stream>>>(S, rw, rb, gamma, beta);
        pv_kernel<<<dim3(16, 8, B), dim3(256), 0, stream>>>(S, vc, xb, 0);
    } else {
        for (int b = 0; b < B; ++b) {
            qk_kernel<<<dim3(16, 16, 8), dim3(256), 0, stream>>>(qc, kc, S, b);
            softmax_reattn<<<dim3(N, 1), dim3(256), 0, stream>>>(S, rw, rb, gamma, beta);
            pv_kernel<<<dim3(16, 8, 1), dim3(256), 0, stream>>>(S, vc, xb, b);
        }
    }

    proj_kernel<<<dim3(64, 12), dim3(256), 0, stream>>>(xb, pw, pb, out);
}

// Round 3
// 268.324 us; speedup vs baseline: 2.5236x; 2.5236x over previous
//
#include <hip/hip_runtime.h>
#include <hip/hip_bf16.h>
#include <math.h>

// Problem constants
#define B 4
#define N 1024
#define C 768
#define H 8
#define D 96

typedef _Float16 half8 __attribute__((ext_vector_type(8)));
typedef _Float16 half4 __attribute__((ext_vector_type(4)));
typedef float f32x4 __attribute__((ext_vector_type(4)));

#define BN_RSQ 0.9999950000374997f   // 1/sqrt(1+1e-5)
#define QK_SCALE 0.10206207261596577f // 96^-0.5

// ---------------------------------------------------------------------------
// K1: per-token 3x3 conv, SAME padding, (3,16,16) images. f32 in -> f16 out.
// ---------------------------------------------------------------------------
__global__ __launch_bounds__(256) void conv_tok(const float* __restrict__ x,
                                                const float* __restrict__ w,
                                                _Float16* __restrict__ out) {
    __shared__ float sx[768];
    __shared__ float sw[81];
    int t = blockIdx.x;
    const float* xt = x + (size_t)t * 768;
    int tid = threadIdx.x;
    sx[tid]       = xt[tid];
    sx[tid + 256] = xt[tid + 256];
    sx[tid + 512] = xt[tid + 512];
    if (tid < 81) sw[tid] = w[tid];
    __syncthreads();
    int i = tid >> 4, j = tid & 15;
    float acc0 = 0.f, acc1 = 0.f, acc2 = 0.f;
    #pragma unroll
    for (int c = 0; c < 3; ++c) {
        #pragma unroll
        for (int di = 0; di < 3; ++di) {
            int ii = i + di - 1;
            if (ii < 0 || ii > 15) continue;
            #pragma unroll
            for (int dj = 0; dj < 3; ++dj) {
                int jj = j + dj - 1;
                if (jj < 0 || jj > 15) continue;
                float xv = sx[c * 256 + ii * 16 + jj];
                acc0 += xv * sw[(0 * 3 + c) * 9 + di * 3 + dj];
                acc1 += xv * sw[(1 * 3 + c) * 9 + di * 3 + dj];
                acc2 += xv * sw[(2 * 3 + c) * 9 + di * 3 + dj];
            }
        }
    }
    _Float16* ot = out + (size_t)t * 768;
    ot[0 * 256 + tid] = (_Float16)acc0;
    ot[1 * 256 + tid] = (_Float16)acc1;
    ot[2 * 256 + tid] = (_Float16)acc2;
}

// ---------------------------------------------------------------------------
// K2: transpose V: vcT[b*768 + c][m] = vcH[b*N + m][c]   (f16)
// grid (16 n-tiles, 12 c-tiles, B), 64x64 tiles.
// ---------------------------------------------------------------------------
__global__ __launch_bounds__(256) void transpose_v(const _Float16* __restrict__ vcH,
                                                   _Float16* __restrict__ vcT) {
    __shared__ _Float16 tile[64][66];
    int n0 = blockIdx.x * 64, c0 = blockIdx.y * 64, b = blockIdx.z;
    int tid = threadIdx.x;
    for (int i = tid; i < 4096; i += 256) {
        int r = i >> 6, c = i & 63;
        tile[r][c] = vcH[((size_t)(b * N + n0 + r)) * C + c0 + c];
    }
    __syncthreads();
    for (int i = tid; i < 4096; i += 256) {
        int cr = i >> 6, nc = i & 63;
        vcT[((size_t)(b * 768 + c0 + cr)) * N + n0 + nc] = tile[nc][cr];
    }
}

// ---------------------------------------------------------------------------
// K3: vsum[b][c] = sum_m vcH[b][m][c]  (partial over 64 rows, atomicAdd)
// grid (12, 16): x: (b,c) flat/256 ; y: m-range of 64.
// ---------------------------------------------------------------------------
__global__ __launch_bounds__(256) void vsum_part(const _Float16* __restrict__ vcH,
                                                 float* __restrict__ vsum) {
    int col = blockIdx.x * 256 + threadIdx.x;   // 0..3071
    int b = col / 768, c = col - b * 768;
    int m0 = blockIdx.y * 64;
    float s = 0.f;
    #pragma unroll 8
    for (int m = 0; m < 64; ++m)
        s += (float)vcH[((size_t)(b * N) + m0 + m) * C + c];
    atomicAdd(&vsum[b * 768 + c], s);
}

// ---------------------------------------------------------------------------
// K4: QK^T with f16 MFMA. Writes expS (f16, no max-subtraction: |S|<~2) and
// atomicAdds row sums into Lrow. grid (8,8,32): 128x128 tile per (b,h).
// ---------------------------------------------------------------------------
__global__ __launch_bounds__(256) void qk_mfma(const _Float16* __restrict__ qcH,
                                               const _Float16* __restrict__ kcH,
                                               _Float16* __restrict__ expS,
                                               float* __restrict__ Lrow) {
    __shared__ _Float16 Qt[128 * 96];
    __shared__ _Float16 Kt[128 * 96];
    const int n0 = blockIdx.x * 128, m0 = blockIdx.y * 128, z = blockIdx.z;
    const int b = z >> 3, h = z & 7;
    const int tid = threadIdx.x;
    const _Float16* qg = qcH + ((size_t)(b * N + n0)) * C + h * D;
    const _Float16* kg = kcH + ((size_t)(b * N + m0)) * C + h * D;
    char* Qb = (char*)Qt;
    char* Kb = (char*)Kt;
    #pragma unroll
    for (int it = 0; it < 6; ++it) {
        int chunk = it * 256 + tid;          // 0..1535
        int r = chunk / 12, cc = (chunk - r * 12) * 8;
        half8 qv = *(const half8*)(qg + (size_t)r * C + cc);
        half8 kv = *(const half8*)(kg + (size_t)r * C + cc);
        int off = ((r * 96 + cc) * 2) ^ ((r & 7) << 4);
        *(half8*)(Qb + off) = qv;
        *(half8*)(Kb + off) = kv;
    }
    __syncthreads();
    const int wid = tid >> 6, lane = tid & 63;
    const int wr = wid >> 1, wc = wid & 1;
    const int l15 = lane & 15, l4 = lane >> 4;
    f32x4 acc[4][4] = {};
    #pragma unroll
    for (int ks = 0; ks < 3; ++ks) {
        int k0 = ks * 32 + l4 * 8;
        half8 a[4], bf[4];
        #pragma unroll
        for (int fm = 0; fm < 4; ++fm) {
            int row = wr * 64 + fm * 16 + l15;
            a[fm] = *(half8*)(Qb + (((row * 96 + k0) * 2) ^ ((row & 7) << 4)));
        }
        #pragma unroll
        for (int fn = 0; fn < 4; ++fn) {
            int row = wc * 64 + fn * 16 + l15;
            bf[fn] = *(half8*)(Kb + (((row * 96 + k0) * 2) ^ ((row & 7) << 4)));
        }
        #pragma unroll
        for (int fm = 0; fm < 4; ++fm)
            #pragma unroll
            for (int fn = 0; fn < 4; ++fn)
                acc[fm][fn] = __builtin_amdgcn_mfma_f32_16x16x32_f16(a[fm], bf[fn], acc[fm][fn], 0, 0, 0);
    }
    // exp, store f16, row-sum -> atomicAdd Lrow
    #pragma unroll
    for (int fm = 0; fm < 4; ++fm) {
        #pragma unroll
        for (int j = 0; j < 4; ++j) {
            int row = n0 + wr * 64 + fm * 16 + l4 * 4 + j;
            float rs = 0.f;
            #pragma unroll
            for (int fn = 0; fn < 4; ++fn) {
                float p = __expf(acc[fm][fn][j] * QK_SCALE);
                rs += p;
                int m = m0 + wc * 64 + fn * 16 + l15;
                expS[((size_t)z * N + row) * N + m] = (_Float16)p;
            }
            rs += __shfl_xor(rs, 1);
            rs += __shfl_xor(rs, 2);
            rs += __shfl_xor(rs, 4);
            rs += __shfl_xor(rs, 8);
            if (l15 == 0) atomicAdd(&Lrow[z * N + row], rs);
        }
    }
}

// ---------------------------------------------------------------------------
// K5: fused normalize + re-attention head-mix + PV (f16 MFMA).
// grid (16 n-tiles, 4 m-splits, B), block 512 (8 waves, wave = head-group g).
// x partial results accumulated via atomicAdd (x pre-zeroed).
// ---------------------------------------------------------------------------
__global__ __launch_bounds__(512, 2) void pv_fused(const _Float16* __restrict__ expS,
                                                   const float* __restrict__ Lrow,
                                                   const _Float16* __restrict__ vcT,
                                                   const float* __restrict__ rw,
                                                   const float* __restrict__ gamma,
                                                   float* __restrict__ x) {
    __shared__ _Float16 AL[8 * 64 * 32];   // 32 KB  A' tiles, [g][n][m] swizzled
    __shared__ _Float16 VL[8 * 96 * 32];   // 48 KB  V^T tiles, [g][d][m] swizzled
    __shared__ float w2s[64];
    const int n0 = blockIdx.x * 64;
    const int mbase = blockIdx.y * 256;
    const int b = blockIdx.z;
    const int tid = threadIdx.x;
    if (tid < 64) {
        int g = tid >> 3, hh = tid & 7;
        w2s[tid] = gamma[g] * BN_RSQ * rw[g * 8 + hh];
    }
    const int n_t = tid >> 3;          // 0..63: this thread's n row (mix phase)
    const int mq = (tid & 7) * 4;      // 0..28: m quad within subtile
    float IL[8];
    #pragma unroll
    for (int h = 0; h < 8; ++h)
        IL[h] = 1.0f / Lrow[(b * 8 + h) * N + n0 + n_t];
    __syncthreads();
    const int wid = tid >> 6, lane = tid & 63;
    const int l15 = lane & 15, l4 = lane >> 4;
    char* ALb = (char*)AL;
    char* VLb = (char*)VL;
    f32x4 acc[4][6] = {};
    for (int msub = 0; msub < 8; ++msub) {
        const int m0 = mbase + msub * 32;
        // phase 1: global loads (issue early)
        half4 sE[8];
        #pragma unroll
        for (int h = 0; h < 8; ++h)
            sE[h] = *(const half4*)(expS + ((size_t)(b * 8 + h) * N + n0 + n_t) * N + m0 + mq);
        half8 vv[6];
        int voff[6];
        #pragma unroll
        for (int it = 0; it < 6; ++it) {
            int q = it * 512 + tid;          // 0..3071
            int g = q / 384, r = q - g * 384;
            int d = r >> 2, m4 = (r & 3) * 8;
            vv[it] = *(const half8*)(vcT + ((size_t)(b * 768 + g * 96 + d)) * N + m0 + m4);
            voff[it] = g * 6144 + (((d * 32 + m4) * 2) ^ ((d & 7) << 4));
        }
        // normalize
        f32x4 Pq[8];
        #pragma unroll
        for (int h = 0; h < 8; ++h) {
            #pragma unroll
            for (int i = 0; i < 4; ++i) Pq[h][i] = (float)sE[h][i] * IL[h];
        }
        __syncthreads();   // prev MFMA done reading LDS
        // mix + write A' (f16)
        #pragma unroll
        for (int g = 0; g < 8; ++g) {
            f32x4 v = {};
            #pragma unroll
            for (int h = 0; h < 8; ++h) {
                float wv = w2s[g * 8 + h];
                #pragma unroll
                for (int i = 0; i < 4; ++i) v[i] += wv * Pq[h][i];
            }
            half4 hv;
            #pragma unroll
            for (int i = 0; i < 4; ++i) hv[i] = (_Float16)v[i];
            *(half4*)(ALb + (g * 4096 + (((n_t * 32 + mq) * 2) ^ ((n_t & 7) << 4)))) = hv;
        }
        #pragma unroll
        for (int it = 0; it < 6; ++it)
            *(half8*)(VLb + voff[it]) = vv[it];
        __syncthreads();
        // MFMA: wave wid owns head-group g = wid
        half8 af[4];
        #pragma unroll
        for (int fm = 0; fm < 4; ++fm) {
            int n = fm * 16 + l15;
            af[fm] = *(half8*)(ALb + wid * 4096 + (((n * 32 + l4 * 8) * 2) ^ ((n & 7) << 4)));
        }
        #pragma unroll
        for (int fn = 0; fn < 6; ++fn) {
            int d = fn * 16 + l15;
            half8 bf = *(half8*)(VLb + wid * 6144 + (((d * 32 + l4 * 8) * 2) ^ ((d & 7) << 4)));
            #pragma unroll
            for (int fm = 0; fm < 4; ++fm)
                acc[fm][fn] = __builtin_amdgcn_mfma_f32_16x16x32_f16(af[fm], bf, acc[fm][fn], 0, 0, 0);
        }
    }
    #pragma unroll
    for (int fm = 0; fm < 4; ++fm)
        #pragma unroll
        for (int fn = 0; fn < 6; ++fn)
            #pragma unroll
            for (int j = 0; j < 4; ++j) {
                int n = n0 + fm * 16 + l4 * 4 + j;
                int c = wid * 96 + fn * 16 + l15;
                atomicAdd(&x[((size_t)(b * N + n)) * C + c], acc[fm][fn][j]);
            }
}

// ---------------------------------------------------------------------------
// K6: projection out = (x + cg*vsum) @ pw^T + pb  with f16 MFMA.
// grid (32 t-tiles x128, 8 c'-tiles x96). block 256 (4 waves, 2x2).
// ---------------------------------------------------------------------------
__global__ __launch_bounds__(256) void proj_mfma(const float* __restrict__ x,
                                                 const float* __restrict__ vsum,
                                                 const float* __restrict__ pw,
                                                 const float* __restrict__ pb,
                                                 const float* __restrict__ rb,
                                                 const float* __restrict__ gamma,
                                                 const float* __restrict__ beta,
                                                 float* __restrict__ out) {
    __shared__ _Float16 sX[128 * 32];
    __shared__ _Float16 sW[96 * 32];
    const int t0 = blockIdx.x * 128, c0 = blockIdx.y * 96;
    const int b = t0 >> 10;
    const int tid = threadIdx.x;
    const int wid = tid >> 6, lane = tid & 63;
    const int wr = wid >> 1, wc = wid & 1;
    const int l15 = lane & 15, l4 = lane >> 4;
    char* Xb = (char*)sX;
    char* Wb = (char*)sW;
    f32x4 acc[4][3] = {};
    for (int k0 = 0; k0 < 768; k0 += 32) {
        __syncthreads();   // prev MFMA done
        // stage X (+ cg*vsum term), 128x32 f32 -> f16
        #pragma unroll
        for (int it = 0; it < 4; ++it) {
            int q = it * 256 + tid;            // 0..1023
            int r = q >> 3, c4 = (q & 7) * 4;
            f32x4 xv = *(const f32x4*)(x + (size_t)(t0 + r) * C + k0 + c4);
            int g = (k0 + c4) / 96;
            float cg = gamma[g] * BN_RSQ * rb[g] + beta[g];
            const f32x4 vs = *(const f32x4*)(vsum + b * 768 + k0 + c4);
            half4 hv;
            #pragma unroll
            for (int i = 0; i < 4; ++i) hv[i] = (_Float16)(xv[i] + cg * vs[i]);
            *(half4*)(Xb + (((r * 32 + c4) * 2) ^ ((r & 7) << 4))) = hv;
        }
        // stage W, 96x32 f32 -> f16
        #pragma unroll
        for (int it = 0; it < 3; ++it) {
            int q = it * 256 + tid;            // 0..767
            int r = q >> 3, c4 = (q & 7) * 4;
            f32x4 wv = *(const f32x4*)(pw + (size_t)(c0 + r) * C + k0 + c4);
            half4 hv;
            #pragma unroll
            for (int i = 0; i < 4; ++i) hv[i] = (_Float16)wv[i];
            *(half4*)(Wb + (((r * 32 + c4) * 2) ^ ((r & 7) << 4))) = hv;
        }
        __syncthreads();
        half8 af[4];
        #pragma unroll
        for (int fm = 0; fm < 4; ++fm) {
            int r = wr * 64 + fm * 16 + l15;
            af[fm] = *(half8*)(Xb + (((r * 32 + l4 * 8) * 2) ^ ((r & 7) << 4)));
        }
        #pragma unroll
        for (int fn = 0; fn < 3; ++fn) {
            int r = wc * 48 + fn * 16 + l15;
            half8 bf = *(half8*)(Wb + (((r * 32 + l4 * 8) * 2) ^ ((r & 7) << 4)));
            #pragma unroll
            for (int fm = 0; fm < 4; ++fm)
                acc[fm][fn] = __builtin_amdgcn_mfma_f32_16x16x32_f16(af[fm], bf, acc[fm][fn], 0, 0, 0);
        }
    }
    #pragma unroll
    for (int fm = 0; fm < 4; ++fm)
        #pragma unroll
        for (int fn = 0; fn < 3; ++fn) {
            int cc = c0 + wc * 48 + fn * 16 + l15;
            float bias = pb[cc];
            #pragma unroll
            for (int j = 0; j < 4; ++j) {
                int t = t0 + wr * 64 + fm * 16 + l4 * 4 + j;
                out[(size_t)t * C + cc] = acc[fm][fn][j] + bias;
            }
        }
}

// ---------------------------------------------------------------------------
extern "C" void kernel_launch(void* const* d_in, const int* in_sizes, int n_in,
                              void* d_out, int out_size, void* d_ws, size_t ws_size,
                              hipStream_t stream) {
    const float* q     = (const float*)d_in[0];
    const float* k     = (const float*)d_in[1];
    const float* v     = (const float*)d_in[2];
    const float* qw    = (const float*)d_in[3];
    const float* kw    = (const float*)d_in[4];
    const float* vw    = (const float*)d_in[5];
    const float* rw    = (const float*)d_in[6];
    const float* rb    = (const float*)d_in[7];
    const float* gamma = (const float*)d_in[8];
    const float* beta  = (const float*)d_in[9];
    const float* pw    = (const float*)d_in[10];
    const float* pb    = (const float*)d_in[11];
    float* out = (float*)d_out;

    // Workspace layout (bytes, all 256-aligned):
    char* ws = (char*)d_ws;
    _Float16* expS = (_Float16*)ws;                       // 67,108,864 B
    float*    xacc = (float*)(ws + 67108864);             // 12,582,912 B
    _Float16* qcH  = (_Float16*)(ws + 79691776);          //  6,291,456 B
    _Float16* kcH  = (_Float16*)(ws + 85983232);
    _Float16* vcH  = (_Float16*)(ws + 92274688);
    _Float16* vcT  = (_Float16*)(ws + 98566144);
    float*    Lrow = (float*)(ws + 104857600);            //    131,072 B
    float*    vsum = (float*)(ws + 104988672);            //     12,288 B
    // total ~105 MB (ws_size >= 185 MB verified by round-2 batched path)

    hipMemsetAsync(Lrow, 0, 131072, stream);
    hipMemsetAsync(xacc, 0, 12582912, stream);
    hipMemsetAsync(vsum, 0, 12288, stream);

    conv_tok<<<dim3(B * N), dim3(256), 0, stream>>>(q, qw, qcH);
    conv_tok<<<dim3(B * N), dim3(256), 0, stream>>>(k, kw, kcH);
    conv_tok<<<dim3(B * N), dim3(256), 0, stream>>>(v, vw, vcH);

    transpose_v<<<dim3(16, 12, B), dim3(256), 0, stream>>>(vcH, vcT);
    vsum_part<<<dim3(12, 16), dim3(256), 0, stream>>>(vcH, vsum);

    qk_mfma<<<dim3(8, 8, 8 * B), dim3(256), 0, stream>>>(qcH, kcH, expS, Lrow);

    pv_fused<<<dim3(16, 4, B), dim3(512), 0, stream>>>(expS, Lrow, vcT, rw, gamma, xacc);

    proj_mfma<<<dim3(32, 8), dim3(256), 0, stream>>>(xacc, vsum, pw, pb, rb, gamma, beta, out);
}

// Round 7
// 262.439 us; speedup vs baseline: 2.5802x; 1.0224x over previous
//
#include <hip/hip_runtime.h>
#include <hip/hip_bf16.h>
#include <math.h>

// Problem constants
#define B 4
#define N 1024
#define C 768
#define H 8
#define D 96

typedef _Float16 half8 __attribute__((ext_vector_type(8)));
typedef _Float16 half4 __attribute__((ext_vector_type(4)));
typedef float f32x4 __attribute__((ext_vector_type(4)));

#define BN_RSQ 0.9999950000374997f    // 1/sqrt(1+1e-5)
#define QK_SCALE 0.10206207261596577f // 96^-0.5

// ---------------------------------------------------------------------------
// K1: per-token 3x3 conv, SAME padding, (3,16,16) images. f32 in -> f16 out.
// ---------------------------------------------------------------------------
__global__ __launch_bounds__(256) void conv_tok(const float* __restrict__ x,
                                                const float* __restrict__ w,
                                                _Float16* __restrict__ out) {
    __shared__ float sx[768];
    __shared__ float sw[81];
    int t = blockIdx.x;
    const float* xt = x + (size_t)t * 768;
    int tid = threadIdx.x;
    sx[tid]       = xt[tid];
    sx[tid + 256] = xt[tid + 256];
    sx[tid + 512] = xt[tid + 512];
    if (tid < 81) sw[tid] = w[tid];
    __syncthreads();
    int i = tid >> 4, j = tid & 15;
    float acc0 = 0.f, acc1 = 0.f, acc2 = 0.f;
    #pragma unroll
    for (int c = 0; c < 3; ++c) {
        #pragma unroll
        for (int di = 0; di < 3; ++di) {
            int ii = i + di - 1;
            if (ii < 0 || ii > 15) continue;
            #pragma unroll
            for (int dj = 0; dj < 3; ++dj) {
                int jj = j + dj - 1;
                if (jj < 0 || jj > 15) continue;
                float xv = sx[c * 256 + ii * 16 + jj];
                acc0 += xv * sw[(0 * 3 + c) * 9 + di * 3 + dj];
                acc1 += xv * sw[(1 * 3 + c) * 9 + di * 3 + dj];
                acc2 += xv * sw[(2 * 3 + c) * 9 + di * 3 + dj];
            }
        }
    }
    _Float16* ot = out + (size_t)t * 768;
    ot[0 * 256 + tid] = (_Float16)acc0;
    ot[1 * 256 + tid] = (_Float16)acc1;
    ot[2 * 256 + tid] = (_Float16)acc2;
}

// ---------------------------------------------------------------------------
// K2: transpose V: vcT[b*768 + c][m] = vcH[b*N + m][c]   (f16)
// ---------------------------------------------------------------------------
__global__ __launch_bounds__(256) void transpose_v(const _Float16* __restrict__ vcH,
                                                   _Float16* __restrict__ vcT) {
    __shared__ _Float16 tile[64][66];
    int n0 = blockIdx.x * 64, c0 = blockIdx.y * 64, b = blockIdx.z;
    int tid = threadIdx.x;
    for (int i = tid; i < 4096; i += 256) {
        int r = i >> 6, c = i & 63;
        tile[r][c] = vcH[((size_t)(b * N + n0 + r)) * C + c0 + c];
    }
    __syncthreads();
    for (int i = tid; i < 4096; i += 256) {
        int cr = i >> 6, nc = i & 63;
        vcT[((size_t)(b * 768 + c0 + cr)) * N + n0 + nc] = tile[nc][cr];
    }
}

// ---------------------------------------------------------------------------
// K3: vsum[row] = sum_m vcT[row][m], row = b*768+c. One wave per row.
// ---------------------------------------------------------------------------
__global__ __launch_bounds__(256) void vsum_row(const _Float16* __restrict__ vcT,
                                                float* __restrict__ vsum) {
    int row = blockIdx.x * 4 + (threadIdx.x >> 6);
    int lane = threadIdx.x & 63;
    const _Float16* p = vcT + (size_t)row * N;
    float s = 0.f;
    #pragma unroll
    for (int it = 0; it < 2; ++it) {
        half8 v = *(const half8*)(p + (it * 64 + lane) * 8);
        #pragma unroll
        for (int i = 0; i < 8; ++i) s += (float)v[i];
    }
    #pragma unroll
    for (int off = 1; off < 64; off <<= 1) s += __shfl_xor(s, off);
    if (lane == 0) vsum[row] = s;
}

// ---------------------------------------------------------------------------
// K4: QK^T with f16 MFMA (R3-verified layout). Writes expS (f16) via LDS
// staging (coalesced half8 rows) and atomicAdds row sums into Lrow.
// grid (8,8,32): 128x128 tile per (b,h). block 256 (4 waves, 2x2).
// ---------------------------------------------------------------------------
__global__ __launch_bounds__(256) void qk_mfma(const _Float16* __restrict__ qcH,
                                               const _Float16* __restrict__ kcH,
                                               _Float16* __restrict__ expS,
                                               float* __restrict__ Lrow) {
    __shared__ __align__(16) char smem[49152];   // Q(24K) | K(24K); reused: P staging 128x136 f16
    char* Qb = smem;
    char* Kb = smem + 24576;
    const int n0 = blockIdx.x * 128, m0 = blockIdx.y * 128, z = blockIdx.z;
    const int b = z >> 3, h = z & 7;
    const int tid = threadIdx.x;
    const _Float16* qg = qcH + ((size_t)(b * N + n0)) * C + h * D;
    const _Float16* kg = kcH + ((size_t)(b * N + m0)) * C + h * D;
    #pragma unroll
    for (int it = 0; it < 6; ++it) {
        int chunk = it * 256 + tid;          // 0..1535
        int r = chunk / 12, cc = (chunk - r * 12) * 8;
        half8 qv = *(const half8*)(qg + (size_t)r * C + cc);
        half8 kv = *(const half8*)(kg + (size_t)r * C + cc);
        int off = ((r * 96 + cc) * 2) ^ ((r & 7) << 4);
        *(half8*)(Qb + off) = qv;
        *(half8*)(Kb + off) = kv;
    }
    __syncthreads();
    const int wid = tid >> 6, lane = tid & 63;
    const int wr = wid >> 1, wc = wid & 1;
    const int l15 = lane & 15, l4 = lane >> 4;
    f32x4 acc[4][4] = {};
    #pragma unroll
    for (int ks = 0; ks < 3; ++ks) {
        int k0 = ks * 32 + l4 * 8;
        half8 a[4], bf[4];
        #pragma unroll
        for (int fm = 0; fm < 4; ++fm) {
            int row = wr * 64 + fm * 16 + l15;
            a[fm] = *(half8*)(Qb + (((row * 96 + k0) * 2) ^ ((row & 7) << 4)));
        }
        #pragma unroll
        for (int fn = 0; fn < 4; ++fn) {
            int row = wc * 64 + fn * 16 + l15;
            bf[fn] = *(half8*)(Kb + (((row * 96 + k0) * 2) ^ ((row & 7) << 4)));
        }
        #pragma unroll
        for (int fm = 0; fm < 4; ++fm)
            #pragma unroll
            for (int fn = 0; fn < 4; ++fn)
                acc[fm][fn] = __builtin_amdgcn_mfma_f32_16x16x32_f16(a[fm], bf[fn], acc[fm][fn], 0, 0, 0);
    }
    __syncthreads();   // all waves done reading Qb/Kb; smem reused for P staging
    // exp -> LDS staging (rows padded to 136), row sums -> atomicAdd Lrow
    #pragma unroll
    for (int fm = 0; fm < 4; ++fm) {
        #pragma unroll
        for (int j = 0; j < 4; ++j) {
            int row = wr * 64 + fm * 16 + l4 * 4 + j;
            float rs = 0.f;
            #pragma unroll
            for (int fn = 0; fn < 4; ++fn) {
                float p = __expf(acc[fm][fn][j] * QK_SCALE);
                rs += p;
                int col = wc * 64 + fn * 16 + l15;
                *(_Float16*)(smem + (row * 136 + col) * 2) = (_Float16)p;
            }
            rs += __shfl_xor(rs, 1);
            rs += __shfl_xor(rs, 2);
            rs += __shfl_xor(rs, 4);
            rs += __shfl_xor(rs, 8);
            if (l15 == 0) atomicAdd(&Lrow[z * N + n0 + row], rs);
        }
    }
    __syncthreads();
    // coalesced store: half8 per thread, 256B contiguous per 16-thread group
    _Float16* eg = expS + ((size_t)z * N + n0) * N + m0;
    #pragma unroll
    for (int it = 0; it < 8; ++it) {
        int q2 = it * 256 + tid;             // 0..2047
        int row = q2 >> 4, col8 = (q2 & 15) * 8;
        half8 v = *(half8*)(smem + (row * 136 + col8) * 2);
        *(half8*)(eg + (size_t)row * N + col8) = v;
    }
}

// ---------------------------------------------------------------------------
// K5: fused normalize + re-attention head-mix + PV (f16 MFMA).
// grid (16 n-tiles, 4 m-splits, B), block 512 (8 waves, wave = head-group g).
// V fed directly from global vcT (L2-resident); x accumulated via atomicAdd.
// ---------------------------------------------------------------------------
__global__ __launch_bounds__(512, 2) void pv_fused(const _Float16* __restrict__ expS,
                                                   const float* __restrict__ Lrow,
                                                   const _Float16* __restrict__ vcT,
                                                   const float* __restrict__ rw,
                                                   const float* __restrict__ gamma,
                                                   float* __restrict__ x) {
    __shared__ _Float16 AL[8 * 64 * 32];   // 32 KB  A' tiles, [g][n][m] swizzled
    __shared__ float w2s[64];
    const int n0 = blockIdx.x * 64;
    const int mbase = blockIdx.y * 256;
    const int b = blockIdx.z;
    const int tid = threadIdx.x;
    if (tid < 64) {
        int g = tid >> 3, hh = tid & 7;
        w2s[tid] = gamma[g] * BN_RSQ * rw[g * 8 + hh];
    }
    const int n_t = tid >> 3;          // 0..63: this thread's n row (mix phase)
    const int mq = (tid & 7) * 4;      // 0..28: m quad within subtile
    float IL[8];
    #pragma unroll
    for (int h = 0; h < 8; ++h)
        IL[h] = 1.0f / Lrow[(size_t)(b * 8 + h) * N + n0 + n_t];
    __syncthreads();
    const int wid = tid >> 6, lane = tid & 63;
    const int l15 = lane & 15, l4 = lane >> 4;
    char* ALb = (char*)AL;
    const _Float16* vgbase = vcT + (size_t)(b * 768 + wid * 96) * N;
    f32x4 acc[4][6] = {};
    for (int msub = 0; msub < 8; ++msub) {
        const int m0 = mbase + msub * 32;
        // load expS rows (issue early)
        half4 sE[8];
        #pragma unroll
        for (int h = 0; h < 8; ++h)
            sE[h] = *(const half4*)(expS + ((size_t)(b * 8 + h) * N + n0 + n_t) * N + m0 + mq);
        // normalize
        f32x4 Pq[8];
        #pragma unroll
        for (int h = 0; h < 8; ++h) {
            #pragma unroll
            for (int i = 0; i < 4; ++i) Pq[h][i] = (float)sE[h][i] * IL[h];
        }
        __syncthreads();   // prev MFMA done reading AL
        // mix + write A' (f16)
        #pragma unroll
        for (int g = 0; g < 8; ++g) {
            f32x4 v = {};
            #pragma unroll
            for (int h = 0; h < 8; ++h) {
                float wv = w2s[g * 8 + h];
                #pragma unroll
                for (int i = 0; i < 4; ++i) v[i] += wv * Pq[h][i];
            }
            half4 hv;
            #pragma unroll
            for (int i = 0; i < 4; ++i) hv[i] = (_Float16)v[i];
            *(half4*)(ALb + (g * 4096 + (((n_t * 32 + mq) * 2) ^ ((n_t & 7) << 4)))) = hv;
        }
        __syncthreads();
        // MFMA: wave wid owns head-group g = wid; V direct from global
        half8 af[4];
        #pragma unroll
        for (int fm = 0; fm < 4; ++fm) {
            int n = fm * 16 + l15;
            af[fm] = *(half8*)(ALb + wid * 4096 + (((n * 32 + l4 * 8) * 2) ^ ((n & 7) << 4)));
        }
        #pragma unroll
        for (int fn = 0; fn < 6; ++fn) {
            int d = fn * 16 + l15;
            half8 bf = *(const half8*)(vgbase + (size_t)d * N + m0 + l4 * 8);
            #pragma unroll
            for (int fm = 0; fm < 4; ++fm)
                acc[fm][fn] = __builtin_amdgcn_mfma_f32_16x16x32_f16(af[fm], bf, acc[fm][fn], 0, 0, 0);
        }
    }
    #pragma unroll
    for (int fm = 0; fm < 4; ++fm)
        #pragma unroll
        for (int fn = 0; fn < 6; ++fn)
            #pragma unroll
            for (int j = 0; j < 4; ++j) {
                int n = n0 + fm * 16 + l4 * 4 + j;
                int c = wid * 96 + fn * 16 + l15;
                atomicAdd(&x[((size_t)(b * N + n)) * C + c], acc[fm][fn][j]);
            }
}

// ---------------------------------------------------------------------------
// K6: projection out = (x + cg*vsum) @ pw^T + pb  with f16 MFMA.
// grid (32 t-tiles x128, 8 c'-tiles x96). block 256 (4 waves, 2x2).
// ---------------------------------------------------------------------------
__global__ __launch_bounds__(256) void proj_mfma(const float* __restrict__ x,
                                                 const float* __restrict__ vsum,
                                                 const float* __restrict__ pw,
                                                 const float* __restrict__ pb,
                                                 const float* __restrict__ rb,
                                                 const float* __restrict__ gamma,
                                                 const float* __restrict__ beta,
                                                 float* __restrict__ out) {
    __shared__ _Float16 sX[128 * 32];
    __shared__ _Float16 sW[96 * 32];
    const int t0 = blockIdx.x * 128, c0 = blockIdx.y * 96;
    const int b = t0 >> 10;
    const int tid = threadIdx.x;
    const int wid = tid >> 6, lane = tid & 63;
    const int wr = wid >> 1, wc = wid & 1;
    const int l15 = lane & 15, l4 = lane >> 4;
    char* Xb = (char*)sX;
    char* Wb = (char*)sW;
    f32x4 acc[4][3] = {};
    for (int k0 = 0; k0 < 768; k0 += 32) {
        __syncthreads();   // prev MFMA done
        // stage X (+ cg*vsum term), 128x32 f32 -> f16
        #pragma unroll
        for (int it = 0; it < 4; ++it) {
            int q = it * 256 + tid;            // 0..1023
            int r = q >> 3, c4 = (q & 7) * 4;
            f32x4 xv = *(const f32x4*)(x + (size_t)(t0 + r) * C + k0 + c4);
            int g = (k0 + c4) / 96;
            float cg = gamma[g] * BN_RSQ * rb[g] + beta[g];
            const f32x4 vs = *(const f32x4*)(vsum + b * 768 + k0 + c4);
            half4 hv;
            #pragma unroll
            for (int i = 0; i < 4; ++i) hv[i] = (_Float16)(xv[i] + cg * vs[i]);
            *(half4*)(Xb + (((r * 32 + c4) * 2) ^ ((r & 7) << 4))) = hv;
        }
        // stage W, 96x32 f32 -> f16
        #pragma unroll
        for (int it = 0; it < 3; ++it) {
            int q = it * 256 + tid;            // 0..767
            int r = q >> 3, c4 = (q & 7) * 4;
            f32x4 wv = *(const f32x4*)(pw + (size_t)(c0 + r) * C + k0 + c4);
            half4 hv;
            #pragma unroll
            for (int i = 0; i < 4; ++i) hv[i] = (_Float16)wv[i];
            *(half4*)(Wb + (((r * 32 + c4) * 2) ^ ((r & 7) << 4))) = hv;
        }
        __syncthreads();
        half8 af[4];
        #pragma unroll
        for (int fm = 0; fm < 4; ++fm) {
            int r = wr * 64 + fm * 16 + l15;
            af[fm] = *(half8*)(Xb + (((r * 32 + l4 * 8) * 2) ^ ((r & 7) << 4)));
        }
        #pragma unroll
        for (int fn = 0; fn < 3; ++fn) {
            int r = wc * 48 + fn * 16 + l15;
            half8 bf = *(half8*)(Wb + (((r * 32 + l4 * 8) * 2) ^ ((r & 7) << 4)));
            #pragma unroll
            for (int fm = 0; fm < 4; ++fm)
                acc[fm][fn] = __builtin_amdgcn_mfma_f32_16x16x32_f16(af[fm], bf, acc[fm][fn], 0, 0, 0);
        }
    }
    #pragma unroll
    for (int fm = 0; fm < 4; ++fm)
        #pragma unroll
        for (int fn = 0; fn < 3; ++fn) {
            int cc = c0 + wc * 48 + fn * 16 + l15;
            float bias = pb[cc];
            #pragma unroll
            for (int j = 0; j < 4; ++j) {
                int t = t0 + wr * 64 + fm * 16 + l4 * 4 + j;
                out[(size_t)t * C + cc] = acc[fm][fn][j] + bias;
            }
        }
}

// ---------------------------------------------------------------------------
extern "C" void kernel_launch(void* const* d_in, const int* in_sizes, int n_in,
                              void* d_out, int out_size, void* d_ws, size_t ws_size,
                              hipStream_t stream) {
    const float* q     = (const float*)d_in[0];
    const float* k     = (const float*)d_in[1];
    const float* v     = (const float*)d_in[2];
    const float* qw    = (const float*)d_in[3];
    const float* kw    = (const float*)d_in[4];
    const float* vw    = (const float*)d_in[5];
    const float* rw    = (const float*)d_in[6];
    const float* rb    = (const float*)d_in[7];
    const float* gamma = (const float*)d_in[8];
    const float* beta  = (const float*)d_in[9];
    const float* pw    = (const float*)d_in[10];
    const float* pb    = (const float*)d_in[11];
    float* out = (float*)d_out;

    // Workspace layout (bytes, 256-aligned):
    char* ws = (char*)d_ws;
    _Float16* expS = (_Float16*)ws;                       // 67,108,864 B
    float*    xacc = (float*)(ws + 67108864);             // 12,582,912 B
    _Float16* qcH  = (_Float16*)(ws + 79691776);          //  6,291,456 B
    _Float16* kcH  = (_Float16*)(ws + 85983232);
    _Float16* vcH  = (_Float16*)(ws + 92274688);
    _Float16* vcT  = (_Float16*)(ws + 98566144);
    float*    Lrow = (float*)(ws + 104857600);            //    131,072 B
    float*    vsum = (float*)(ws + 104988672);            //     12,288 B
    // total ~105 MB

    hipMemsetAsync(Lrow, 0, 131072, stream);
    hipMemsetAsync(xacc, 0, 12582912, stream);

    conv_tok<<<dim3(B * N), dim3(256), 0, stream>>>(q, qw, qcH);
    conv_tok<<<dim3(B * N), dim3(256), 0, stream>>>(k, kw, kcH);
    conv_tok<<<dim3(B * N), dim3(256), 0, stream>>>(v, vw, vcH);

    transpose_v<<<dim3(16, 12, B), dim3(256), 0, stream>>>(vcH, vcT);
    vsum_row<<<dim3(768), dim3(256), 0, stream>>>(vcT, vsum);

    qk_mfma<<<dim3(8, 8, 8 * B), dim3(256), 0, stream>>>(qcH, kcH, expS, Lrow);

    pv_fused<<<dim3(16, 4, B), dim3(512), 0, stream>>>(expS, Lrow, vcT, rw, gamma, xacc);

    proj_mfma<<<dim3(32, 8), dim3(256), 0, stream>>>(xacc, vsum, pw, pb, rb, gamma, beta, out);
}